// Round 3
// baseline (939.002 us; speedup 1.0000x reference)
//
#include <hip/hip_runtime.h>

typedef short bf16x8 __attribute__((ext_vector_type(8)));
typedef float f32x4 __attribute__((ext_vector_type(4)));

#define RH 2560   // R*H = 10*256

__device__ __forceinline__ unsigned short f2bf(float f) {
  unsigned u = __float_as_uint(f);
  u += 0x7fffu + ((u >> 16) & 1u);   // RNE
  return (unsigned short)(u >> 16);
}
__device__ __forceinline__ float bf2f(unsigned short s) {
  return __uint_as_float(((unsigned)s) << 16);
}

// ---------------- CSR build over (dst,type) buckets ----------------
__global__ void zero_int(int* __restrict__ p, int n) {
  int i = blockIdx.x * 256 + threadIdx.x;
  if (i < n) p[i] = 0;
}
// key = dst*10 + type
__global__ void hist_kernel(const int* __restrict__ ei, const int* __restrict__ ety,
                            int E, int* __restrict__ cnt) {
  int e = blockIdx.x * 256 + threadIdx.x;
  if (e < E) atomicAdd(&cnt[ei[e] * 10 + ety[e]], 1);
}
// single-pass scan: 1024 threads, ~PER elements serial each, one LDS scan of 1024
__global__ __launch_bounds__(1024) void scan_excl(const int* __restrict__ cnt,
                                                  int* __restrict__ offs, int n) {
  __shared__ int ps[1024];
  const int t = threadIdx.x;
  const int PER = (n + 1023) >> 10;
  const int base = t * PER;
  int s = 0;
  for (int k = 0; k < PER; ++k) {
    int idx = base + k;
    if (idx < n) s += cnt[idx];
  }
  ps[t] = s;
  __syncthreads();
  for (int off = 1; off < 1024; off <<= 1) {
    int add = (t >= off) ? ps[t - off] : 0;
    __syncthreads();
    ps[t] += add;
    __syncthreads();
  }
  int run = t ? ps[t - 1] : 0;
  for (int k = 0; k < PER; ++k) {
    int idx = base + k;
    if (idx < n) { offs[idx] = run; run += cnt[idx]; }
  }
  if (t == 1023) offs[n] = run;
}
__global__ void copy_int(const int* __restrict__ a, int* __restrict__ b, int n) {
  int i = blockIdx.x * 256 + threadIdx.x;
  if (i < n) b[i] = a[i];
}
// sort edge payloads {j, 2*norm} into (dst,type)-bucket order
__global__ void scatter_kernel(const int* __restrict__ ei, const int* __restrict__ ejj,
                               const int* __restrict__ ety, const float* __restrict__ enm,
                               int E, int* __restrict__ cursor, int2* __restrict__ jnpk) {
  int e = blockIdx.x * 256 + threadIdx.x;
  if (e < E) {
    int s = atomicAdd(&cursor[ei[e] * 10 + ety[e]], 1);
    jnpk[s] = make_int2(ejj[e], __float_as_int(enm[e] * 2.0f));
  }
}

// ---------------- weight packing ----------------
__global__ void packW(const float* __restrict__ w, unsigned short* __restrict__ Wt) {
  int idx = blockIdx.x * 256 + threadIdx.x;
  if (idx >= 256 * RH) return;
  int o = idx / RH;
  int k = idx - o * RH;
  Wt[idx] = f2bf(w[(size_t)k * 256 + o]);
}
__global__ void packLin(const float* __restrict__ lw, unsigned short* __restrict__ Wt) {
  int idx = blockIdx.x * 256 + threadIdx.x;
  if (idx >= 256 * 512) return;
  int o = idx >> 9;
  int k = idx & 511;
  Wt[idx] = f2bf(lw[(size_t)k * 256 + o]);
}
// x -> out section 1 (x copy), emotions[:, :256] f32, em16[:, :256] bf16, x16 contiguous bf16
__global__ void copyX(const float* __restrict__ x, float* __restrict__ xcopy,
                      float* __restrict__ em, unsigned short* __restrict__ em16,
                      unsigned short* __restrict__ x16, int total) {
  int idx = blockIdx.x * 256 + threadIdx.x;
  if (idx >= total) return;
  int nrow = idx >> 8, h = idx & 255;
  float v = x[idx];
  xcopy[idx] = v;
  em[(size_t)nrow * 512 + h] = v;
  em16[(size_t)nrow * 512 + h] = f2bf(v);
  x16[idx] = f2bf(v);
}

// ---------------- per-node aggregation -> S [N][2560] bf16 ----------------
// 1 wave per node (4 cols/lane), 4 nodes per block. Relation known statically
// from the (dst,type) bucket -> named register accumulators, no LDS, no syncs.
__global__ __launch_bounds__(256) void agg_kernel3(
    const unsigned short* __restrict__ src,   // [N][256] bf16 contiguous rows
    const int* __restrict__ offs2,            // [N*10+1]
    const int2* __restrict__ jnpk,            // sorted payloads {j, 2*norm}
    unsigned short* __restrict__ S, int N)
{
  const int wave = threadIdx.x >> 6;
  const int lane = threadIdx.x & 63;
  const int node = blockIdx.x * 4 + wave;
  if (node >= N) return;
  const int b10 = node * 10;
  const int cb = lane * 4;                    // 4 columns per lane
  float a0[10], a1[10], a2[10], a3[10];
#pragma unroll
  for (int r = 0; r < 10; ++r) {
    int sb = offs2[b10 + r];
    int se = offs2[b10 + r + 1];
    float b0 = 0.f, b1 = 0.f, b2 = 0.f, b3 = 0.f;
    for (int q = sb; q < se; ++q) {
      int2 jn = jnpk[q];                      // wave-uniform addr -> broadcast
      float nr = __int_as_float(jn.y);
      uint2 v = *reinterpret_cast<const uint2*>(src + (size_t)jn.x * 256 + cb);
      b0 += nr * __uint_as_float(v.x << 16);
      b1 += nr * __uint_as_float(v.x & 0xffff0000u);
      b2 += nr * __uint_as_float(v.y << 16);
      b3 += nr * __uint_as_float(v.y & 0xffff0000u);
    }
    a0[r] = b0; a1[r] = b1; a2[r] = b2; a3[r] = b3;
  }
  int cc = offs2[b10 + 10] - offs2[b10];
  float scale = 1.0f / (float)(cc > 1 ? cc : 1);
  size_t base = (size_t)node * RH + cb;
#pragma unroll
  for (int r = 0; r < 10; ++r) {
    unsigned p0 = (unsigned)f2bf(a0[r] * scale) | ((unsigned)f2bf(a1[r] * scale) << 16);
    unsigned p1 = (unsigned)f2bf(a2[r] * scale) | ((unsigned)f2bf(a3[r] * scale) << 16);
    uint2 pk; pk.x = p0; pk.y = p1;
    *reinterpret_cast<uint2*>(S + base + r * 256) = pk;
  }
}

// ---------------- GEMM: C[M x 256] = A[M x K](bf16) @ Bt[256 x K]^T ----------------
template<int MODE>
__global__ __launch_bounds__(256) void gemm128(
    const unsigned short* __restrict__ A,
    const unsigned short* __restrict__ Bt,
    int M, int K,
    float* __restrict__ fout,
    unsigned short* __restrict__ bout,
    const float* __restrict__ bias)
{
  __shared__ unsigned short At[128][40];
  __shared__ unsigned short Bs[128][40];
  const int tid = threadIdx.x;
  const int tileM = blockIdx.x * 128;
  const int tileN = blockIdx.y * 128;
  const int lane = tid & 63;
  const int wid = tid >> 6;
  const int wr = wid >> 1, wc = wid & 1;
  const int l15 = lane & 15, lq = lane >> 4;
  f32x4 acc[4][4] = {};
  const int nk = K >> 5;
  for (int kt = 0; kt < nk; ++kt) {
    __syncthreads();
#pragma unroll
    for (int p = 0; p < 2; ++p) {
      int c = tid + p * 256;
      int row = c >> 2;
      int ko = (c & 3) * 8;
      int gr = tileM + row;
      uint4 va = make_uint4(0u, 0u, 0u, 0u);
      if (gr < M) va = *reinterpret_cast<const uint4*>(A + (size_t)gr * K + kt * 32 + ko);
      *reinterpret_cast<uint4*>(&At[row][ko]) = va;
      uint4 vb = *reinterpret_cast<const uint4*>(Bt + (size_t)(tileN + row) * K + kt * 32 + ko);
      *reinterpret_cast<uint4*>(&Bs[row][ko]) = vb;
    }
    __syncthreads();
    bf16x8 af[4], bfr[4];
#pragma unroll
    for (int m = 0; m < 4; ++m)
      af[m] = *reinterpret_cast<const bf16x8*>(&At[wr * 64 + m * 16 + l15][lq * 8]);
#pragma unroll
    for (int n = 0; n < 4; ++n)
      bfr[n] = *reinterpret_cast<const bf16x8*>(&Bs[wc * 64 + n * 16 + l15][lq * 8]);
#pragma unroll
    for (int m = 0; m < 4; ++m)
#pragma unroll
      for (int n = 0; n < 4; ++n)
        acc[m][n] = __builtin_amdgcn_mfma_f32_16x16x32_bf16(af[m], bfr[n], acc[m][n], 0, 0, 0);
  }
  const int r0 = tileM + wr * 64;
  const int c0 = tileN + wc * 64;
#pragma unroll
  for (int m = 0; m < 4; ++m) {
#pragma unroll
    for (int n = 0; n < 4; ++n) {
      int col = c0 + n * 16 + l15;
      int rowb = r0 + m * 16 + lq * 4;
#pragma unroll
      for (int q = 0; q < 4; ++q) {
        int row = rowb + q;
        if (row < M) {
          float v = acc[m][n][q];
          if (MODE == 0) {
            float s = 1.0f / (1.0f + __expf(-v));
            bout[(size_t)row * 256 + col] = f2bf(s);
          } else if (MODE == 1) {
            fout[(size_t)row * 512 + col] = v;
            bout[(size_t)row * 512 + col] = f2bf(v);
          } else {
            float s = v + bias[col];
            s = s > 0.0f ? s : 0.0f;
            fout[(size_t)row * 256 + col] = s;
          }
        }
      }
    }
  }
}

// ---------------- fc + log_softmax ----------------
__global__ __launch_bounds__(256) void fc_lsm(const float* __restrict__ hidden,
                                              const float* __restrict__ fcW,
                                              const float* __restrict__ fcb,
                                              float* __restrict__ outlp, int N) {
  __shared__ float hs[32 * 256];
  __shared__ float fw[256 * 7];
  __shared__ float lg[32][8];
  const int t = threadIdx.x;
  const int nb = blockIdx.x * 32;
  for (int c = t; c < 256 * 7; c += 256) fw[c] = fcW[c];
  for (int c = t; c < 32 * 256; c += 256) {
    int node = nb + (c >> 8);
    hs[c] = (node < N) ? hidden[(size_t)node * 256 + (c & 255)] : 0.0f;
  }
  __syncthreads();
  if (t < 224) {
    int ln = t / 7, c = t - ln * 7;
    float s = fcb[c];
    for (int h = 0; h < 256; ++h) s += hs[ln * 256 + h] * fw[h * 7 + c];
    lg[ln][c] = s;
  }
  __syncthreads();
  if (t < 32 && nb + t < N) {
    float m = lg[t][0];
    for (int c = 1; c < 7; ++c) m = fmaxf(m, lg[t][c]);
    float sum = 0.0f;
    for (int c = 0; c < 7; ++c) sum += __expf(lg[t][c] - m);
    float ls = __logf(sum);
    for (int c = 0; c < 7; ++c) outlp[(size_t)(nb + t) * 7 + c] = lg[t][c] - m - ls;
  }
}

extern "C" void kernel_launch(void* const* d_in, const int* in_sizes, int n_in,
                              void* d_out, int out_size, void* d_ws, size_t ws_size,
                              hipStream_t stream) {
  const float* x     = (const float*)d_in[1];
  const int*   ei    = (const int*)d_in[2];     // [2][E]: row0 = dst i, row1 = src j
  const float* enorm = (const float*)d_in[3];
  const int*   etype = (const int*)d_in[4];
  const float* w1    = (const float*)d_in[7];
  const float* w2    = (const float*)d_in[8];
  const float* linW  = (const float*)d_in[9];
  const float* linb  = (const float*)d_in[10];
  const float* fcW   = (const float*)d_in[11];
  const float* fcb   = (const float*)d_in[12];
  float* out = (float*)d_out;

  const int N = in_sizes[0];        // 20000
  const int E = in_sizes[3];        // 640000
  const int NB = N * 10;            // (dst,type) buckets

  char* ws = (char*)d_ws;
  size_t off = 0;
  auto carve = [&](size_t bytes) -> void* {
    void* p = ws + off;
    off += (bytes + 255) & ~(size_t)255;
    return p;
  };
  unsigned short* S    = (unsigned short*)carve((size_t)N * RH * 2);
  unsigned short* W1t  = (unsigned short*)carve((size_t)256 * RH * 2);
  unsigned short* W2t  = (unsigned short*)carve((size_t)256 * RH * 2);
  unsigned short* LWt  = (unsigned short*)carve((size_t)256 * 512 * 2);
  unsigned short* out1 = (unsigned short*)carve((size_t)N * 256 * 2);
  unsigned short* em16 = (unsigned short*)carve((size_t)N * 512 * 2);
  unsigned short* x16  = (unsigned short*)carve((size_t)N * 256 * 2);
  int* cnt2            = (int*)carve((size_t)NB * 4);
  int* offs2           = (int*)carve((size_t)(NB + 1) * 4);
  int* cursor          = (int*)carve((size_t)NB * 4);
  int2* jnpk           = (int2*)carve((size_t)E * 8);
  float* hidden        = (float*)S;   // alias: S dead after gemm2, hidden born at gemm3

  const int* e_i = ei;       // destination (aggregate here)
  const int* e_j = ei + E;   // source (gather x here)

  // (dst,type) CSR + payload sort
  zero_int<<<(NB + 255) / 256, 256, 0, stream>>>(cnt2, NB);
  hist_kernel<<<(E + 255) / 256, 256, 0, stream>>>(e_i, etype, E, cnt2);
  scan_excl<<<1, 1024, 0, stream>>>(cnt2, offs2, NB);
  copy_int<<<(NB + 255) / 256, 256, 0, stream>>>(offs2, cursor, NB);
  scatter_kernel<<<(E + 255) / 256, 256, 0, stream>>>(e_i, e_j, etype, enorm, E,
                                                      cursor, jnpk);

  // weight packing + x copies
  packW<<<(256 * RH + 255) / 256, 256, 0, stream>>>(w1, W1t);
  packW<<<(256 * RH + 255) / 256, 256, 0, stream>>>(w2, W2t);
  packLin<<<(256 * 512 + 255) / 256, 256, 0, stream>>>(linW, LWt);
  copyX<<<((N * 256) + 255) / 256, 256, 0, stream>>>(
      x, out + (size_t)N * 7, out + (size_t)N * 263, em16, x16, N * 256);

  dim3 gemm_grid((N + 127) / 128, 2);

  // layer 1
  agg_kernel3<<<(N + 3) / 4, 256, 0, stream>>>(x16, offs2, jnpk, S, N);
  gemm128<0><<<gemm_grid, 256, 0, stream>>>(S, W1t, N, RH, nullptr, out1, nullptr);

  // layer 2 -> emotions[:, 256:512] (f32 into d_out) + bf16 copy into em16
  agg_kernel3<<<(N + 3) / 4, 256, 0, stream>>>(out1, offs2, jnpk, S, N);
  gemm128<1><<<gemm_grid, 256, 0, stream>>>(S, W2t, N, RH,
      out + (size_t)N * 263 + 256, em16 + 256, nullptr);

  // hidden = relu(emotions @ lin_W + lin_b)
  gemm128<2><<<gemm_grid, 256, 0, stream>>>(em16, LWt, N, 512, hidden, nullptr, linb);

  // logits + log_softmax
  fc_lsm<<<(N + 31) / 32, 256, 0, stream>>>(hidden, fcW, fcb, out, N);
}

// Round 5
// 591.666 us; speedup vs baseline: 1.5870x; 1.5870x over previous
//
#include <hip/hip_runtime.h>

typedef short bf16x8 __attribute__((ext_vector_type(8)));
typedef float f32x4 __attribute__((ext_vector_type(4)));

#define RH 2560   // R*H = 10*256

__device__ __forceinline__ unsigned short f2bf(float f) {
  unsigned u = __float_as_uint(f);
  u += 0x7fffu + ((u >> 16) & 1u);   // RNE
  return (unsigned short)(u >> 16);
}
__device__ __forceinline__ float bf2f(unsigned short s) {
  return __uint_as_float(((unsigned)s) << 16);
}

// ---------------- CSR build over (dst,type) buckets ----------------
__global__ void zero_int(int* __restrict__ p, int n) {
  int i = blockIdx.x * 256 + threadIdx.x;
  if (i < n) p[i] = 0;
}
// key = dst*10 + type
__global__ void hist_kernel(const int* __restrict__ ei, const int* __restrict__ ety,
                            int E, int* __restrict__ cnt) {
  int e = blockIdx.x * 256 + threadIdx.x;
  if (e < E) atomicAdd(&cnt[ei[e] * 10 + ety[e]], 1);
}

// ---- hierarchical exclusive scan: local -> blocksums -> add ----
// level 1: each block scans 4096 elements (1024 thr x 4), writes block total
__global__ __launch_bounds__(1024) void scan_local(const int* __restrict__ cnt,
                                                   int* __restrict__ offs,
                                                   int* __restrict__ bsum, int n) {
  __shared__ int ps[1024];
  const int t = threadIdx.x;
  const int base = blockIdx.x * 4096 + t * 4;
  int v0 = (base + 0 < n) ? cnt[base + 0] : 0;
  int v1 = (base + 1 < n) ? cnt[base + 1] : 0;
  int v2 = (base + 2 < n) ? cnt[base + 2] : 0;
  int v3 = (base + 3 < n) ? cnt[base + 3] : 0;
  int s = v0 + v1 + v2 + v3;
  ps[t] = s;
  __syncthreads();
  for (int off = 1; off < 1024; off <<= 1) {
    int add = (t >= off) ? ps[t - off] : 0;
    __syncthreads();
    ps[t] += add;
    __syncthreads();
  }
  int run = t ? ps[t - 1] : 0;
  if (base + 0 < n) offs[base + 0] = run; run += v0;
  if (base + 1 < n) offs[base + 1] = run; run += v1;
  if (base + 2 < n) offs[base + 2] = run; run += v2;
  if (base + 3 < n) offs[base + 3] = run;
  if (t == 1023) bsum[blockIdx.x] = ps[1023];
}
// level 2: single block exclusive-scans the block sums (nb <= 1024),
// also writes grand total into offs[n]
__global__ __launch_bounds__(1024) void scan_bsum(int* __restrict__ bsum,
                                                  int* __restrict__ offs,
                                                  int nb, int n) {
  __shared__ int ps[1024];
  const int t = threadIdx.x;
  int v = (t < nb) ? bsum[t] : 0;
  ps[t] = v;
  __syncthreads();
  for (int off = 1; off < 1024; off <<= 1) {
    int add = (t >= off) ? ps[t - off] : 0;
    __syncthreads();
    ps[t] += add;
    __syncthreads();
  }
  if (t < nb) bsum[t] = ps[t] - v;          // exclusive
  if (t == nb - 1) offs[n] = ps[t];          // grand total
}
// level 3: add scanned block offset to each chunk
__global__ __launch_bounds__(1024) void scan_add(int* __restrict__ offs,
                                                 const int* __restrict__ bsum, int n) {
  const int add = bsum[blockIdx.x];
  const int base = blockIdx.x * 4096 + threadIdx.x * 4;
#pragma unroll
  for (int k = 0; k < 4; ++k) {
    int idx = base + k;
    if (idx < n) offs[idx] += add;
  }
}

__global__ void copy_int(const int* __restrict__ a, int* __restrict__ b, int n) {
  int i = blockIdx.x * 256 + threadIdx.x;
  if (i < n) b[i] = a[i];
}
// sort edge payloads {j, 2*norm} into (dst,type)-bucket order
__global__ void scatter_kernel(const int* __restrict__ ei, const int* __restrict__ ejj,
                               const int* __restrict__ ety, const float* __restrict__ enm,
                               int E, int* __restrict__ cursor, int2* __restrict__ jnpk) {
  int e = blockIdx.x * 256 + threadIdx.x;
  if (e < E) {
    int s = atomicAdd(&cursor[ei[e] * 10 + ety[e]], 1);
    jnpk[s] = make_int2(ejj[e], __float_as_int(enm[e] * 2.0f));
  }
}

// ---------------- weight packing ----------------
__global__ void packW(const float* __restrict__ w, unsigned short* __restrict__ Wt) {
  int idx = blockIdx.x * 256 + threadIdx.x;
  if (idx >= 256 * RH) return;
  int o = idx / RH;
  int k = idx - o * RH;
  Wt[idx] = f2bf(w[(size_t)k * 256 + o]);
}
__global__ void packLin(const float* __restrict__ lw, unsigned short* __restrict__ Wt) {
  int idx = blockIdx.x * 256 + threadIdx.x;
  if (idx >= 256 * 512) return;
  int o = idx >> 9;
  int k = idx & 511;
  Wt[idx] = f2bf(lw[(size_t)k * 256 + o]);
}
// x -> out section 1 (x copy), emotions[:, :256] f32, em16[:, :256] bf16, x16 contiguous bf16
__global__ void copyX(const float* __restrict__ x, float* __restrict__ xcopy,
                      float* __restrict__ em, unsigned short* __restrict__ em16,
                      unsigned short* __restrict__ x16, int total) {
  int idx = blockIdx.x * 256 + threadIdx.x;
  if (idx >= total) return;
  int nrow = idx >> 8, h = idx & 255;
  float v = x[idx];
  xcopy[idx] = v;
  em[(size_t)nrow * 512 + h] = v;
  em16[(size_t)nrow * 512 + h] = f2bf(v);
  x16[idx] = f2bf(v);
}

// ---------------- per-node aggregation -> S [N][2560] bf16 ----------------
// 1 wave per node (4 cols/lane), 4 nodes per block. Relation known statically
// from the (dst,type) bucket -> named register accumulators, no LDS, no syncs.
__global__ __launch_bounds__(256) void agg_kernel3(
    const unsigned short* __restrict__ src,   // [N][256] bf16 contiguous rows
    const int* __restrict__ offs2,            // [N*10+1]
    const int2* __restrict__ jnpk,            // sorted payloads {j, 2*norm}
    unsigned short* __restrict__ S, int N)
{
  const int wave = threadIdx.x >> 6;
  const int lane = threadIdx.x & 63;
  const int node = blockIdx.x * 4 + wave;
  if (node >= N) return;
  const int b10 = node * 10;
  const int cb = lane * 4;                    // 4 columns per lane
  float a0[10], a1[10], a2[10], a3[10];
#pragma unroll
  for (int r = 0; r < 10; ++r) {
    int sb = offs2[b10 + r];
    int se = offs2[b10 + r + 1];
    float b0 = 0.f, b1 = 0.f, b2 = 0.f, b3 = 0.f;
    for (int q = sb; q < se; ++q) {
      int2 jn = jnpk[q];                      // wave-uniform addr -> broadcast
      float nr = __int_as_float(jn.y);
      uint2 v = *reinterpret_cast<const uint2*>(src + (size_t)jn.x * 256 + cb);
      b0 += nr * __uint_as_float(v.x << 16);
      b1 += nr * __uint_as_float(v.x & 0xffff0000u);
      b2 += nr * __uint_as_float(v.y << 16);
      b3 += nr * __uint_as_float(v.y & 0xffff0000u);
    }
    a0[r] = b0; a1[r] = b1; a2[r] = b2; a3[r] = b3;
  }
  int cc = offs2[b10 + 10] - offs2[b10];
  float scale = 1.0f / (float)(cc > 1 ? cc : 1);
  size_t base = (size_t)node * RH + cb;
#pragma unroll
  for (int r = 0; r < 10; ++r) {
    unsigned p0 = (unsigned)f2bf(a0[r] * scale) | ((unsigned)f2bf(a1[r] * scale) << 16);
    unsigned p1 = (unsigned)f2bf(a2[r] * scale) | ((unsigned)f2bf(a3[r] * scale) << 16);
    uint2 pk; pk.x = p0; pk.y = p1;
    *reinterpret_cast<uint2*>(S + base + r * 256) = pk;
  }
}

// ---------------- GEMM: C[M x 256] = A[M x K](bf16) @ Bt[256 x K]^T ----------------
template<int MODE>
__global__ __launch_bounds__(256) void gemm128(
    const unsigned short* __restrict__ A,
    const unsigned short* __restrict__ Bt,
    int M, int K,
    float* __restrict__ fout,
    unsigned short* __restrict__ bout,
    const float* __restrict__ bias)
{
  __shared__ unsigned short At[128][40];
  __shared__ unsigned short Bs[128][40];
  const int tid = threadIdx.x;
  const int tileM = blockIdx.x * 128;
  const int tileN = blockIdx.y * 128;
  const int lane = tid & 63;
  const int wid = tid >> 6;
  const int wr = wid >> 1, wc = wid & 1;
  const int l15 = lane & 15, lq = lane >> 4;
  f32x4 acc[4][4] = {};
  const int nk = K >> 5;
  for (int kt = 0; kt < nk; ++kt) {
    __syncthreads();
#pragma unroll
    for (int p = 0; p < 2; ++p) {
      int c = tid + p * 256;
      int row = c >> 2;
      int ko = (c & 3) * 8;
      int gr = tileM + row;
      uint4 va = make_uint4(0u, 0u, 0u, 0u);
      if (gr < M) va = *reinterpret_cast<const uint4*>(A + (size_t)gr * K + kt * 32 + ko);
      *reinterpret_cast<uint4*>(&At[row][ko]) = va;
      uint4 vb = *reinterpret_cast<const uint4*>(Bt + (size_t)(tileN + row) * K + kt * 32 + ko);
      *reinterpret_cast<uint4*>(&Bs[row][ko]) = vb;
    }
    __syncthreads();
    bf16x8 af[4], bfr[4];
#pragma unroll
    for (int m = 0; m < 4; ++m)
      af[m] = *reinterpret_cast<const bf16x8*>(&At[wr * 64 + m * 16 + l15][lq * 8]);
#pragma unroll
    for (int n = 0; n < 4; ++n)
      bfr[n] = *reinterpret_cast<const bf16x8*>(&Bs[wc * 64 + n * 16 + l15][lq * 8]);
#pragma unroll
    for (int m = 0; m < 4; ++m)
#pragma unroll
      for (int n = 0; n < 4; ++n)
        acc[m][n] = __builtin_amdgcn_mfma_f32_16x16x32_bf16(af[m], bfr[n], acc[m][n], 0, 0, 0);
  }
  const int r0 = tileM + wr * 64;
  const int c0 = tileN + wc * 64;
#pragma unroll
  for (int m = 0; m < 4; ++m) {
#pragma unroll
    for (int n = 0; n < 4; ++n) {
      int col = c0 + n * 16 + l15;
      int rowb = r0 + m * 16 + lq * 4;
#pragma unroll
      for (int q = 0; q < 4; ++q) {
        int row = rowb + q;
        if (row < M) {
          float v = acc[m][n][q];
          if (MODE == 0) {
            float s = 1.0f / (1.0f + __expf(-v));
            bout[(size_t)row * 256 + col] = f2bf(s);
          } else if (MODE == 1) {
            fout[(size_t)row * 512 + col] = v;
            bout[(size_t)row * 512 + col] = f2bf(v);
          } else {
            float s = v + bias[col];
            s = s > 0.0f ? s : 0.0f;
            fout[(size_t)row * 256 + col] = s;
          }
        }
      }
    }
  }
}

// ---------------- fc + log_softmax ----------------
__global__ __launch_bounds__(256) void fc_lsm(const float* __restrict__ hidden,
                                              const float* __restrict__ fcW,
                                              const float* __restrict__ fcb,
                                              float* __restrict__ outlp, int N) {
  __shared__ float hs[32 * 256];
  __shared__ float fw[256 * 7];
  __shared__ float lg[32][8];
  const int t = threadIdx.x;
  const int nb = blockIdx.x * 32;
  for (int c = t; c < 256 * 7; c += 256) fw[c] = fcW[c];
  for (int c = t; c < 32 * 256; c += 256) {
    int node = nb + (c >> 8);
    hs[c] = (node < N) ? hidden[(size_t)node * 256 + (c & 255)] : 0.0f;
  }
  __syncthreads();
  if (t < 224) {
    int ln = t / 7, c = t - ln * 7;
    float s = fcb[c];
    for (int h = 0; h < 256; ++h) s += hs[ln * 256 + h] * fw[h * 7 + c];
    lg[ln][c] = s;
  }
  __syncthreads();
  if (t < 32 && nb + t < N) {
    float m = lg[t][0];
    for (int c = 1; c < 7; ++c) m = fmaxf(m, lg[t][c]);
    float sum = 0.0f;
    for (int c = 0; c < 7; ++c) sum += __expf(lg[t][c] - m);
    float ls = __logf(sum);
    for (int c = 0; c < 7; ++c) outlp[(size_t)(nb + t) * 7 + c] = lg[t][c] - m - ls;
  }
}

extern "C" void kernel_launch(void* const* d_in, const int* in_sizes, int n_in,
                              void* d_out, int out_size, void* d_ws, size_t ws_size,
                              hipStream_t stream) {
  const float* x     = (const float*)d_in[1];
  const int*   ei    = (const int*)d_in[2];     // [2][E]: row0 = dst i, row1 = src j
  const float* enorm = (const float*)d_in[3];
  const int*   etype = (const int*)d_in[4];
  const float* w1    = (const float*)d_in[7];
  const float* w2    = (const float*)d_in[8];
  const float* linW  = (const float*)d_in[9];
  const float* linb  = (const float*)d_in[10];
  const float* fcW   = (const float*)d_in[11];
  const float* fcb   = (const float*)d_in[12];
  float* out = (float*)d_out;

  const int N = in_sizes[0];        // 20000
  const int E = in_sizes[3];        // 640000
  const int NB = N * 10;            // (dst,type) buckets
  const int NSCAN = (NB + 4095) / 4096;   // scan level-1 blocks (49 for N=20000)

  char* ws = (char*)d_ws;
  size_t off = 0;
  auto carve = [&](size_t bytes) -> void* {
    void* p = ws + off;
    off += (bytes + 255) & ~(size_t)255;
    return p;
  };
  unsigned short* S    = (unsigned short*)carve((size_t)N * RH * 2);
  unsigned short* W1t  = (unsigned short*)carve((size_t)256 * RH * 2);
  unsigned short* W2t  = (unsigned short*)carve((size_t)256 * RH * 2);
  unsigned short* LWt  = (unsigned short*)carve((size_t)256 * 512 * 2);
  unsigned short* out1 = (unsigned short*)carve((size_t)N * 256 * 2);
  unsigned short* em16 = (unsigned short*)carve((size_t)N * 512 * 2);
  unsigned short* x16  = (unsigned short*)carve((size_t)N * 256 * 2);
  int* cnt2            = (int*)carve((size_t)NB * 4);
  int* offs2           = (int*)carve((size_t)(NB + 1) * 4);
  int* cursor          = (int*)carve((size_t)NB * 4);
  int* bsum            = (int*)carve((size_t)1024 * 4);
  int2* jnpk           = (int2*)carve((size_t)E * 8);
  float* hidden        = (float*)S;   // alias: S dead after gemm2, hidden born at gemm3

  const int* e_i = ei;       // destination (aggregate here)
  const int* e_j = ei + E;   // source (gather x here)

  // (dst,type) CSR + payload sort
  zero_int<<<(NB + 255) / 256, 256, 0, stream>>>(cnt2, NB);
  hist_kernel<<<(E + 255) / 256, 256, 0, stream>>>(e_i, etype, E, cnt2);
  scan_local<<<NSCAN, 1024, 0, stream>>>(cnt2, offs2, bsum, NB);
  scan_bsum<<<1, 1024, 0, stream>>>(bsum, offs2, NSCAN, NB);
  scan_add<<<NSCAN, 1024, 0, stream>>>(offs2, bsum, NB);
  copy_int<<<(NB + 255) / 256, 256, 0, stream>>>(offs2, cursor, NB);
  scatter_kernel<<<(E + 255) / 256, 256, 0, stream>>>(e_i, e_j, etype, enorm, E,
                                                      cursor, jnpk);

  // weight packing + x copies
  packW<<<(256 * RH + 255) / 256, 256, 0, stream>>>(w1, W1t);
  packW<<<(256 * RH + 255) / 256, 256, 0, stream>>>(w2, W2t);
  packLin<<<(256 * 512 + 255) / 256, 256, 0, stream>>>(linW, LWt);
  copyX<<<((N * 256) + 255) / 256, 256, 0, stream>>>(
      x, out + (size_t)N * 7, out + (size_t)N * 263, em16, x16, N * 256);

  dim3 gemm_grid((N + 127) / 128, 2);

  // layer 1
  agg_kernel3<<<(N + 3) / 4, 256, 0, stream>>>(x16, offs2, jnpk, S, N);
  gemm128<0><<<gemm_grid, 256, 0, stream>>>(S, W1t, N, RH, nullptr, out1, nullptr);

  // layer 2 -> emotions[:, 256:512] (f32 into d_out) + bf16 copy into em16
  agg_kernel3<<<(N + 3) / 4, 256, 0, stream>>>(out1, offs2, jnpk, S, N);
  gemm128<1><<<gemm_grid, 256, 0, stream>>>(S, W2t, N, RH,
      out + (size_t)N * 263 + 256, em16 + 256, nullptr);

  // hidden = relu(emotions @ lin_W + lin_b)
  gemm128<2><<<gemm_grid, 256, 0, stream>>>(em16, LWt, N, 512, hidden, nullptr, linb);

  // logits + log_softmax
  fc_lsm<<<(N + 31) / 32, 256, 0, stream>>>(hidden, fcW, fcb, out, N);
}

// Round 7
// 521.787 us; speedup vs baseline: 1.7996x; 1.1339x over previous
//
#include <hip/hip_runtime.h>

typedef short bf16x8 __attribute__((ext_vector_type(8)));
typedef float f32x4 __attribute__((ext_vector_type(4)));

#define RH 2560   // R*H = 10*256

__device__ __forceinline__ unsigned short f2bf(float f) {
  unsigned u = __float_as_uint(f);
  u += 0x7fffu + ((u >> 16) & 1u);   // RNE
  return (unsigned short)(u >> 16);
}
__device__ __forceinline__ float bf2f(unsigned short s) {
  return __uint_as_float(((unsigned)s) << 16);
}

// ---------------- CSR build over (dst,type) buckets ----------------
__global__ void zero_int(int* __restrict__ p, int n) {
  int i = blockIdx.x * 256 + threadIdx.x;
  if (i < n) p[i] = 0;
}
// key = dst*10 + type
__global__ void hist_kernel(const int* __restrict__ ei, const int* __restrict__ ety,
                            int E, int* __restrict__ cnt) {
  int e = blockIdx.x * 256 + threadIdx.x;
  if (e < E) atomicAdd(&cnt[ei[e] * 10 + ety[e]], 1);
}

// ---- hierarchical exclusive scan: local -> blocksums -> add ----
__global__ __launch_bounds__(1024) void scan_local(const int* __restrict__ cnt,
                                                   int* __restrict__ offs,
                                                   int* __restrict__ bsum, int n) {
  __shared__ int ps[1024];
  const int t = threadIdx.x;
  const int base = blockIdx.x * 4096 + t * 4;
  int v0 = (base + 0 < n) ? cnt[base + 0] : 0;
  int v1 = (base + 1 < n) ? cnt[base + 1] : 0;
  int v2 = (base + 2 < n) ? cnt[base + 2] : 0;
  int v3 = (base + 3 < n) ? cnt[base + 3] : 0;
  int s = v0 + v1 + v2 + v3;
  ps[t] = s;
  __syncthreads();
  for (int off = 1; off < 1024; off <<= 1) {
    int add = (t >= off) ? ps[t - off] : 0;
    __syncthreads();
    ps[t] += add;
    __syncthreads();
  }
  int run = t ? ps[t - 1] : 0;
  if (base + 0 < n) offs[base + 0] = run; run += v0;
  if (base + 1 < n) offs[base + 1] = run; run += v1;
  if (base + 2 < n) offs[base + 2] = run; run += v2;
  if (base + 3 < n) offs[base + 3] = run;
  if (t == 1023) bsum[blockIdx.x] = ps[1023];
}
__global__ __launch_bounds__(1024) void scan_bsum(int* __restrict__ bsum,
                                                  int* __restrict__ offs,
                                                  int nb, int n) {
  __shared__ int ps[1024];
  const int t = threadIdx.x;
  int v = (t < nb) ? bsum[t] : 0;
  ps[t] = v;
  __syncthreads();
  for (int off = 1; off < 1024; off <<= 1) {
    int add = (t >= off) ? ps[t - off] : 0;
    __syncthreads();
    ps[t] += add;
    __syncthreads();
  }
  if (t < nb) bsum[t] = ps[t] - v;          // exclusive
  if (t == nb - 1) offs[n] = ps[t];          // grand total
}
__global__ __launch_bounds__(1024) void scan_add(int* __restrict__ offs,
                                                 const int* __restrict__ bsum, int n) {
  const int add = bsum[blockIdx.x];
  const int base = blockIdx.x * 4096 + threadIdx.x * 4;
#pragma unroll
  for (int k = 0; k < 4; ++k) {
    int idx = base + k;
    if (idx < n) offs[idx] += add;
  }
}

__global__ void copy_int(const int* __restrict__ a, int* __restrict__ b, int n) {
  int i = blockIdx.x * 256 + threadIdx.x;
  if (i < n) b[i] = a[i];
}
// sort edge payloads {j, 2*norm} into (dst,type)-bucket order
__global__ void scatter_kernel(const int* __restrict__ ei, const int* __restrict__ ejj,
                               const int* __restrict__ ety, const float* __restrict__ enm,
                               int E, int* __restrict__ cursor, int2* __restrict__ jnpk) {
  int e = blockIdx.x * 256 + threadIdx.x;
  if (e < E) {
    int s = atomicAdd(&cursor[ei[e] * 10 + ety[e]], 1);
    jnpk[s] = make_int2(ejj[e], __float_as_int(enm[e] * 2.0f));
  }
}

// ---------------- weight packing ----------------
__global__ void packW(const float* __restrict__ w, unsigned short* __restrict__ Wt) {
  int idx = blockIdx.x * 256 + threadIdx.x;
  if (idx >= 256 * RH) return;
  int o = idx / RH;
  int k = idx - o * RH;
  Wt[idx] = f2bf(w[(size_t)k * 256 + o]);
}
__global__ void packLin(const float* __restrict__ lw, unsigned short* __restrict__ Wt) {
  int idx = blockIdx.x * 256 + threadIdx.x;
  if (idx >= 256 * 512) return;
  int o = idx >> 9;
  int k = idx & 511;
  Wt[idx] = f2bf(lw[(size_t)k * 256 + o]);
}
__global__ void copyX(const float* __restrict__ x, float* __restrict__ xcopy,
                      float* __restrict__ em, unsigned short* __restrict__ em16,
                      unsigned short* __restrict__ x16, int total) {
  int idx = blockIdx.x * 256 + threadIdx.x;
  if (idx >= total) return;
  int nrow = idx >> 8, h = idx & 255;
  float v = x[idx];
  xcopy[idx] = v;
  em[(size_t)nrow * 512 + h] = v;
  em16[(size_t)nrow * 512 + h] = f2bf(v);
  x16[idx] = f2bf(v);
}

// ---------------- per-bucket aggregation -> S [N][2560] bf16 ----------------
// 1 wave per (node,relation) bucket (200k waves): max TLP for the latency-bound
// gather; 4 cols/lane; pair-unrolled edge loop for ILP-2. Empty buckets write 0.
__global__ __launch_bounds__(256) void agg_bucket(
    const unsigned short* __restrict__ src,   // [N][256] bf16 contiguous rows
    const int* __restrict__ offs2,            // [N*10+1]
    const int2* __restrict__ jnpk,            // sorted payloads {j, 2*norm}
    unsigned short* __restrict__ S, int NB)
{
  const int bucket = blockIdx.x * 4 + (threadIdx.x >> 6);
  if (bucket >= NB) return;
  const int lane = threadIdx.x & 63;
  const int cb = lane * 4;
  const int node = bucket / 10;
  const int r = bucket - node * 10;
  const int b10 = node * 10;
  const int sb = offs2[bucket], se = offs2[bucket + 1];
  const int cc = offs2[b10 + 10] - offs2[b10];
  const float scale = 1.0f / (float)(cc > 1 ? cc : 1);
  float b0 = 0.f, b1 = 0.f, b2 = 0.f, b3 = 0.f;
  int q = sb;
  for (; q + 2 <= se; q += 2) {
    int2 e0 = jnpk[q];
    int2 e1 = jnpk[q + 1];
    float n0 = __int_as_float(e0.y);
    float n1 = __int_as_float(e1.y);
    uint2 v0 = *reinterpret_cast<const uint2*>(src + (size_t)e0.x * 256 + cb);
    uint2 v1 = *reinterpret_cast<const uint2*>(src + (size_t)e1.x * 256 + cb);
    b0 += n0 * __uint_as_float(v0.x << 16);
    b1 += n0 * __uint_as_float(v0.x & 0xffff0000u);
    b2 += n0 * __uint_as_float(v0.y << 16);
    b3 += n0 * __uint_as_float(v0.y & 0xffff0000u);
    b0 += n1 * __uint_as_float(v1.x << 16);
    b1 += n1 * __uint_as_float(v1.x & 0xffff0000u);
    b2 += n1 * __uint_as_float(v1.y << 16);
    b3 += n1 * __uint_as_float(v1.y & 0xffff0000u);
  }
  if (q < se) {
    int2 e0 = jnpk[q];
    float n0 = __int_as_float(e0.y);
    uint2 v0 = *reinterpret_cast<const uint2*>(src + (size_t)e0.x * 256 + cb);
    b0 += n0 * __uint_as_float(v0.x << 16);
    b1 += n0 * __uint_as_float(v0.x & 0xffff0000u);
    b2 += n0 * __uint_as_float(v0.y << 16);
    b3 += n0 * __uint_as_float(v0.y & 0xffff0000u);
  }
  unsigned p0 = (unsigned)f2bf(b0 * scale) | ((unsigned)f2bf(b1 * scale) << 16);
  unsigned p1 = (unsigned)f2bf(b2 * scale) | ((unsigned)f2bf(b3 * scale) << 16);
  uint2 pk; pk.x = p0; pk.y = p1;
  *reinterpret_cast<uint2*>(S + (size_t)node * RH + r * 256 + cb) = pk;
}

// ---------------- GEMM: C[M x 256] = A[M x K](bf16) @ Bt[256 x K]^T ----------------
// 64x128 tile (grid 313x2 = 626 blocks): 2-3 blocks/CU resident so the per-K-iter
// barrier drain overlaps across blocks (was 1 block/CU at 128x128, MfmaUtil 12%).
template<int MODE>
__global__ __launch_bounds__(256) void gemm128(
    const unsigned short* __restrict__ A,
    const unsigned short* __restrict__ Bt,
    int M, int K,
    float* __restrict__ fout,
    unsigned short* __restrict__ bout,
    const float* __restrict__ bias)
{
  __shared__ unsigned short At[64][40];
  __shared__ unsigned short Bs[128][40];
  const int tid = threadIdx.x;
  const int tileM = blockIdx.x * 64;
  const int tileN = blockIdx.y * 128;
  const int lane = tid & 63;
  const int wid = tid >> 6;
  const int wr = wid >> 1, wc = wid & 1;
  const int l15 = lane & 15, lq = lane >> 4;
  f32x4 acc[2][4] = {};
  const int nk = K >> 5;
  for (int kt = 0; kt < nk; ++kt) {
    __syncthreads();
    {
      // A: 64 rows x 32 k -> 256 uint4 slots, 1 per thread
      int row = tid >> 2;
      int ko = (tid & 3) * 8;
      int gr = tileM + row;
      uint4 va = make_uint4(0u, 0u, 0u, 0u);
      if (gr < M) va = *reinterpret_cast<const uint4*>(A + (size_t)gr * K + kt * 32 + ko);
      *reinterpret_cast<uint4*>(&At[row][ko]) = va;
      // B: 128 rows x 32 k -> 512 slots, 2 per thread
#pragma unroll
      for (int p = 0; p < 2; ++p) {
        int c = tid + p * 256;
        int brow = c >> 2;
        int bko = (c & 3) * 8;
        uint4 vb = *reinterpret_cast<const uint4*>(Bt + (size_t)(tileN + brow) * K + kt * 32 + bko);
        *reinterpret_cast<uint4*>(&Bs[brow][bko]) = vb;
      }
    }
    __syncthreads();
    bf16x8 af[2], bfr[4];
#pragma unroll
    for (int m = 0; m < 2; ++m)
      af[m] = *reinterpret_cast<const bf16x8*>(&At[wr * 32 + m * 16 + l15][lq * 8]);
#pragma unroll
    for (int n = 0; n < 4; ++n)
      bfr[n] = *reinterpret_cast<const bf16x8*>(&Bs[wc * 64 + n * 16 + l15][lq * 8]);
#pragma unroll
    for (int m = 0; m < 2; ++m)
#pragma unroll
      for (int n = 0; n < 4; ++n)
        acc[m][n] = __builtin_amdgcn_mfma_f32_16x16x32_bf16(af[m], bfr[n], acc[m][n], 0, 0, 0);
  }
  const int r0 = tileM + wr * 32;
  const int c0 = tileN + wc * 64;
#pragma unroll
  for (int m = 0; m < 2; ++m) {
#pragma unroll
    for (int n = 0; n < 4; ++n) {
      int col = c0 + n * 16 + l15;
      int rowb = r0 + m * 16 + lq * 4;
#pragma unroll
      for (int q = 0; q < 4; ++q) {
        int row = rowb + q;
        if (row < M) {
          float v = acc[m][n][q];
          if (MODE == 0) {
            float s = 1.0f / (1.0f + __expf(-v));
            bout[(size_t)row * 256 + col] = f2bf(s);
          } else if (MODE == 1) {
            fout[(size_t)row * 512 + col] = v;
            bout[(size_t)row * 512 + col] = f2bf(v);
          } else {
            float s = v + bias[col];
            s = s > 0.0f ? s : 0.0f;
            fout[(size_t)row * 256 + col] = s;
          }
        }
      }
    }
  }
}

// ---------------- fc + log_softmax ----------------
__global__ __launch_bounds__(256) void fc_lsm(const float* __restrict__ hidden,
                                              const float* __restrict__ fcW,
                                              const float* __restrict__ fcb,
                                              float* __restrict__ outlp, int N) {
  __shared__ float hs[32 * 256];
  __shared__ float fw[256 * 7];
  __shared__ float lg[32][8];
  const int t = threadIdx.x;
  const int nb = blockIdx.x * 32;
  for (int c = t; c < 256 * 7; c += 256) fw[c] = fcW[c];
  for (int c = t; c < 32 * 256; c += 256) {
    int node = nb + (c >> 8);
    hs[c] = (node < N) ? hidden[(size_t)node * 256 + (c & 255)] : 0.0f;
  }
  __syncthreads();
  if (t < 224) {
    int ln = t / 7, c = t - ln * 7;
    float s = fcb[c];
    for (int h = 0; h < 256; ++h) s += hs[ln * 256 + h] * fw[h * 7 + c];
    lg[ln][c] = s;
  }
  __syncthreads();
  if (t < 32 && nb + t < N) {
    float m = lg[t][0];
    for (int c = 1; c < 7; ++c) m = fmaxf(m, lg[t][c]);
    float sum = 0.0f;
    for (int c = 0; c < 7; ++c) sum += __expf(lg[t][c] - m);
    float ls = __logf(sum);
    for (int c = 0; c < 7; ++c) outlp[(size_t)(nb + t) * 7 + c] = lg[t][c] - m - ls;
  }
}

extern "C" void kernel_launch(void* const* d_in, const int* in_sizes, int n_in,
                              void* d_out, int out_size, void* d_ws, size_t ws_size,
                              hipStream_t stream) {
  const float* x     = (const float*)d_in[1];
  const int*   ei    = (const int*)d_in[2];     // [2][E]: row0 = dst i, row1 = src j
  const float* enorm = (const float*)d_in[3];
  const int*   etype = (const int*)d_in[4];
  const float* w1    = (const float*)d_in[7];
  const float* w2    = (const float*)d_in[8];
  const float* linW  = (const float*)d_in[9];
  const float* linb  = (const float*)d_in[10];
  const float* fcW   = (const float*)d_in[11];
  const float* fcb   = (const float*)d_in[12];
  float* out = (float*)d_out;

  const int N = in_sizes[0];        // 20000
  const int E = in_sizes[3];        // 640000
  const int NB = N * 10;            // (dst,type) buckets
  const int NSCAN = (NB + 4095) / 4096;   // scan level-1 blocks (49 for N=20000)

  char* ws = (char*)d_ws;
  size_t off = 0;
  auto carve = [&](size_t bytes) -> void* {
    void* p = ws + off;
    off += (bytes + 255) & ~(size_t)255;
    return p;
  };
  unsigned short* S    = (unsigned short*)carve((size_t)N * RH * 2);
  unsigned short* W1t  = (unsigned short*)carve((size_t)256 * RH * 2);
  unsigned short* W2t  = (unsigned short*)carve((size_t)256 * RH * 2);
  unsigned short* LWt  = (unsigned short*)carve((size_t)256 * 512 * 2);
  unsigned short* out1 = (unsigned short*)carve((size_t)N * 256 * 2);
  unsigned short* em16 = (unsigned short*)carve((size_t)N * 512 * 2);
  unsigned short* x16  = (unsigned short*)carve((size_t)N * 256 * 2);
  int* cnt2            = (int*)carve((size_t)NB * 4);
  int* offs2           = (int*)carve((size_t)(NB + 1) * 4);
  int* cursor          = (int*)carve((size_t)NB * 4);
  int* bsum            = (int*)carve((size_t)1024 * 4);
  int2* jnpk           = (int2*)carve((size_t)E * 8);
  float* hidden        = (float*)S;   // alias: S dead after gemm2, hidden born at gemm3

  const int* e_i = ei;       // destination (aggregate here)
  const int* e_j = ei + E;   // source (gather x here)

  // (dst,type) CSR + payload sort
  zero_int<<<(NB + 255) / 256, 256, 0, stream>>>(cnt2, NB);
  hist_kernel<<<(E + 255) / 256, 256, 0, stream>>>(e_i, etype, E, cnt2);
  scan_local<<<NSCAN, 1024, 0, stream>>>(cnt2, offs2, bsum, NB);
  scan_bsum<<<1, 1024, 0, stream>>>(bsum, offs2, NSCAN, NB);
  scan_add<<<NSCAN, 1024, 0, stream>>>(offs2, bsum, NB);
  copy_int<<<(NB + 255) / 256, 256, 0, stream>>>(offs2, cursor, NB);
  scatter_kernel<<<(E + 255) / 256, 256, 0, stream>>>(e_i, e_j, etype, enorm, E,
                                                      cursor, jnpk);

  // weight packing + x copies
  packW<<<(256 * RH + 255) / 256, 256, 0, stream>>>(w1, W1t);
  packW<<<(256 * RH + 255) / 256, 256, 0, stream>>>(w2, W2t);
  packLin<<<(256 * 512 + 255) / 256, 256, 0, stream>>>(linW, LWt);
  copyX<<<((N * 256) + 255) / 256, 256, 0, stream>>>(
      x, out + (size_t)N * 7, out + (size_t)N * 263, em16, x16, N * 256);

  dim3 gemm_grid((N + 63) / 64, 2);

  // layer 1
  agg_bucket<<<(NB + 3) / 4, 256, 0, stream>>>(x16, offs2, jnpk, S, NB);
  gemm128<0><<<gemm_grid, 256, 0, stream>>>(S, W1t, N, RH, nullptr, out1, nullptr);

  // layer 2 -> emotions[:, 256:512] (f32 into d_out) + bf16 copy into em16
  agg_bucket<<<(NB + 3) / 4, 256, 0, stream>>>(out1, offs2, jnpk, S, NB);
  gemm128<1><<<gemm_grid, 256, 0, stream>>>(S, W2t, N, RH,
      out + (size_t)N * 263 + 256, em16 + 256, nullptr);

  // hidden = relu(emotions @ lin_W + lin_b)
  gemm128<2><<<gemm_grid, 256, 0, stream>>>(em16, LWt, N, 512, hidden, nullptr, linb);

  // logits + log_softmax
  fc_lsm<<<(N + 31) / 32, 256, 0, stream>>>(hidden, fcW, fcb, out, N);
}

// Round 8
// 518.123 us; speedup vs baseline: 1.8123x; 1.0071x over previous
//
#include <hip/hip_runtime.h>

typedef short bf16x8 __attribute__((ext_vector_type(8)));
typedef float f32x4 __attribute__((ext_vector_type(4)));

#define RH 2560   // R*H = 10*256
#define LDSS 56   // LDS row stride (shorts): 112 B, 16B-aligned, conflict-minimal b128

__device__ __forceinline__ unsigned short f2bf(float f) {
  unsigned u = __float_as_uint(f);
  u += 0x7fffu + ((u >> 16) & 1u);   // RNE
  return (unsigned short)(u >> 16);
}
__device__ __forceinline__ float bf2f(unsigned short s) {
  return __uint_as_float(((unsigned)s) << 16);
}

// ---------------- CSR build over (dst,type) buckets ----------------
__global__ void zero_int(int* __restrict__ p, int n) {
  int i = blockIdx.x * 256 + threadIdx.x;
  if (i < n) p[i] = 0;
}
__global__ void hist_kernel(const int* __restrict__ ei, const int* __restrict__ ety,
                            int E, int* __restrict__ cnt) {
  int e = blockIdx.x * 256 + threadIdx.x;
  if (e < E) atomicAdd(&cnt[ei[e] * 10 + ety[e]], 1);
}

// ---- hierarchical exclusive scan: local -> blocksums -> add(+cursor) ----
__global__ __launch_bounds__(1024) void scan_local(const int* __restrict__ cnt,
                                                   int* __restrict__ offs,
                                                   int* __restrict__ bsum, int n) {
  __shared__ int ps[1024];
  const int t = threadIdx.x;
  const int base = blockIdx.x * 4096 + t * 4;
  int v0 = (base + 0 < n) ? cnt[base + 0] : 0;
  int v1 = (base + 1 < n) ? cnt[base + 1] : 0;
  int v2 = (base + 2 < n) ? cnt[base + 2] : 0;
  int v3 = (base + 3 < n) ? cnt[base + 3] : 0;
  int s = v0 + v1 + v2 + v3;
  ps[t] = s;
  __syncthreads();
  for (int off = 1; off < 1024; off <<= 1) {
    int add = (t >= off) ? ps[t - off] : 0;
    __syncthreads();
    ps[t] += add;
    __syncthreads();
  }
  int run = t ? ps[t - 1] : 0;
  if (base + 0 < n) offs[base + 0] = run; run += v0;
  if (base + 1 < n) offs[base + 1] = run; run += v1;
  if (base + 2 < n) offs[base + 2] = run; run += v2;
  if (base + 3 < n) offs[base + 3] = run;
  if (t == 1023) bsum[blockIdx.x] = ps[1023];
}
__global__ __launch_bounds__(1024) void scan_bsum(int* __restrict__ bsum,
                                                  int* __restrict__ offs,
                                                  int nb, int n) {
  __shared__ int ps[1024];
  const int t = threadIdx.x;
  int v = (t < nb) ? bsum[t] : 0;
  ps[t] = v;
  __syncthreads();
  for (int off = 1; off < 1024; off <<= 1) {
    int add = (t >= off) ? ps[t - off] : 0;
    __syncthreads();
    ps[t] += add;
    __syncthreads();
  }
  if (t < nb) bsum[t] = ps[t] - v;          // exclusive
  if (t == nb - 1) offs[n] = ps[t];          // grand total
}
__global__ __launch_bounds__(1024) void scan_add(int* __restrict__ offs,
                                                 int* __restrict__ cursor,
                                                 const int* __restrict__ bsum, int n) {
  const int add = bsum[blockIdx.x];
  const int base = blockIdx.x * 4096 + threadIdx.x * 4;
#pragma unroll
  for (int k = 0; k < 4; ++k) {
    int idx = base + k;
    if (idx < n) { int v = offs[idx] + add; offs[idx] = v; cursor[idx] = v; }
  }
}

// sort edge payloads {j, 2*norm} into (dst,type)-bucket order
__global__ void scatter_kernel(const int* __restrict__ ei, const int* __restrict__ ejj,
                               const int* __restrict__ ety, const float* __restrict__ enm,
                               int E, int* __restrict__ cursor, int2* __restrict__ jnpk) {
  int e = blockIdx.x * 256 + threadIdx.x;
  if (e < E) {
    int s = atomicAdd(&cursor[ei[e] * 10 + ety[e]], 1);
    jnpk[s] = make_int2(ejj[e], __float_as_int(enm[e] * 2.0f));
  }
}

// ---------------- weight packing (fused: W1t, W2t, LWt) ----------------
__global__ void pack_all(const float* __restrict__ w1, const float* __restrict__ w2,
                         const float* __restrict__ lw,
                         unsigned short* __restrict__ W1t, unsigned short* __restrict__ W2t,
                         unsigned short* __restrict__ LWt) {
  const int NW = 256 * RH;
  int idx = blockIdx.x * 256 + threadIdx.x;
  if (idx < NW) {
    int o = idx / RH, k = idx - o * RH;
    W1t[idx] = f2bf(w1[(size_t)k * 256 + o]);
  } else if (idx < 2 * NW) {
    int i2 = idx - NW;
    int o = i2 / RH, k = i2 - o * RH;
    W2t[i2] = f2bf(w2[(size_t)k * 256 + o]);
  } else {
    int i3 = idx - 2 * NW;
    if (i3 < 256 * 512) {
      int o = i3 >> 9, k = i3 & 511;
      LWt[i3] = f2bf(lw[(size_t)k * 256 + o]);
    }
  }
}
__global__ void copyX(const float* __restrict__ x, float* __restrict__ xcopy,
                      float* __restrict__ em, unsigned short* __restrict__ em16,
                      unsigned short* __restrict__ x16, int total) {
  int idx = blockIdx.x * 256 + threadIdx.x;
  if (idx >= total) return;
  int nrow = idx >> 8, h = idx & 255;
  float v = x[idx];
  xcopy[idx] = v;
  em[(size_t)nrow * 512 + h] = v;
  em16[(size_t)nrow * 512 + h] = f2bf(v);
  x16[idx] = f2bf(v);
}

// ---------------- per-bucket aggregation -> S [N][2560] bf16 ----------------
__global__ __launch_bounds__(256) void agg_bucket(
    const unsigned short* __restrict__ src,
    const int* __restrict__ offs2,
    const int2* __restrict__ jnpk,
    unsigned short* __restrict__ S, int NB)
{
  const int bucket = blockIdx.x * 4 + (threadIdx.x >> 6);
  if (bucket >= NB) return;
  const int lane = threadIdx.x & 63;
  const int cb = lane * 4;
  const int node = bucket / 10;
  const int r = bucket - node * 10;
  const int b10 = node * 10;
  const int sb = offs2[bucket], se = offs2[bucket + 1];
  const int cc = offs2[b10 + 10] - offs2[b10];
  const float scale = 1.0f / (float)(cc > 1 ? cc : 1);
  float b0 = 0.f, b1 = 0.f, b2 = 0.f, b3 = 0.f;
  int q = sb;
  for (; q + 2 <= se; q += 2) {
    int2 e0 = jnpk[q];
    int2 e1 = jnpk[q + 1];
    float n0 = __int_as_float(e0.y);
    float n1 = __int_as_float(e1.y);
    uint2 v0 = *reinterpret_cast<const uint2*>(src + (size_t)e0.x * 256 + cb);
    uint2 v1 = *reinterpret_cast<const uint2*>(src + (size_t)e1.x * 256 + cb);
    b0 += n0 * __uint_as_float(v0.x << 16);
    b1 += n0 * __uint_as_float(v0.x & 0xffff0000u);
    b2 += n0 * __uint_as_float(v0.y << 16);
    b3 += n0 * __uint_as_float(v0.y & 0xffff0000u);
    b0 += n1 * __uint_as_float(v1.x << 16);
    b1 += n1 * __uint_as_float(v1.x & 0xffff0000u);
    b2 += n1 * __uint_as_float(v1.y << 16);
    b3 += n1 * __uint_as_float(v1.y & 0xffff0000u);
  }
  if (q < se) {
    int2 e0 = jnpk[q];
    float n0 = __int_as_float(e0.y);
    uint2 v0 = *reinterpret_cast<const uint2*>(src + (size_t)e0.x * 256 + cb);
    b0 += n0 * __uint_as_float(v0.x << 16);
    b1 += n0 * __uint_as_float(v0.x & 0xffff0000u);
    b2 += n0 * __uint_as_float(v0.y << 16);
    b3 += n0 * __uint_as_float(v0.y & 0xffff0000u);
  }
  unsigned p0 = (unsigned)f2bf(b0 * scale) | ((unsigned)f2bf(b1 * scale) << 16);
  unsigned p1 = (unsigned)f2bf(b2 * scale) | ((unsigned)f2bf(b3 * scale) << 16);
  uint2 pk; pk.x = p0; pk.y = p1;
  *reinterpret_cast<uint2*>(S + (size_t)node * RH + r * 256 + cb) = pk;
}

// ------- split-K GEMM: P[kz][M][256] = A[M][K-half] @ Bt[256][K-half]^T (f32) -------
// grid (ceil(M/64), 2, 2): 1252 blocks -> ~5 blocks/CU resident (was 2.4, Occ 21%).
__global__ __launch_bounds__(256) void gemm_sk(
    const unsigned short* __restrict__ A,
    const unsigned short* __restrict__ Bt,
    int M, int K,
    float* __restrict__ P)
{
  __shared__ unsigned short At[64 * LDSS];
  __shared__ unsigned short Bs[128 * LDSS];
  const int tid = threadIdx.x;
  const int tileM = blockIdx.x * 64;
  const int tileN = blockIdx.y * 128;
  const int kbase = blockIdx.z * (K >> 1);
  const int lane = tid & 63;
  const int wid = tid >> 6;
  const int wr = wid >> 1, wc = wid & 1;
  const int l15 = lane & 15, lq = lane >> 4;
  f32x4 acc[2][4] = {};
  const int nk = K >> 6;   // (K/2)/32
  for (int kt = 0; kt < nk; ++kt) {
    __syncthreads();
    {
      int row = tid >> 2;
      int ko = (tid & 3) * 8;
      int gr = tileM + row;
      uint4 va = make_uint4(0u, 0u, 0u, 0u);
      if (gr < M) va = *reinterpret_cast<const uint4*>(A + (size_t)gr * K + kbase + kt * 32 + ko);
      *reinterpret_cast<uint4*>(&At[row * LDSS + ko]) = va;
#pragma unroll
      for (int p = 0; p < 2; ++p) {
        int c = tid + p * 256;
        int brow = c >> 2;
        int bko = (c & 3) * 8;
        uint4 vb = *reinterpret_cast<const uint4*>(Bt + (size_t)(tileN + brow) * K + kbase + kt * 32 + bko);
        *reinterpret_cast<uint4*>(&Bs[brow * LDSS + bko]) = vb;
      }
    }
    __syncthreads();
    bf16x8 af[2], bfr[4];
#pragma unroll
    for (int m = 0; m < 2; ++m)
      af[m] = *reinterpret_cast<const bf16x8*>(&At[(wr * 32 + m * 16 + l15) * LDSS + lq * 8]);
#pragma unroll
    for (int n = 0; n < 4; ++n)
      bfr[n] = *reinterpret_cast<const bf16x8*>(&Bs[(wc * 64 + n * 16 + l15) * LDSS + lq * 8]);
#pragma unroll
    for (int m = 0; m < 2; ++m)
#pragma unroll
      for (int n = 0; n < 4; ++n)
        acc[m][n] = __builtin_amdgcn_mfma_f32_16x16x32_bf16(af[m], bfr[n], acc[m][n], 0, 0, 0);
  }
  float* Pz = P + (size_t)blockIdx.z * M * 256;
  const int r0 = tileM + wr * 32;
  const int c0 = tileN + wc * 64;
#pragma unroll
  for (int m = 0; m < 2; ++m) {
#pragma unroll
    for (int n = 0; n < 4; ++n) {
      int col = c0 + n * 16 + l15;
      int rowb = r0 + m * 16 + lq * 4;
#pragma unroll
      for (int q = 0; q < 4; ++q) {
        int row = rowb + q;
        if (row < M) Pz[(size_t)row * 256 + col] = acc[m][n][q];
      }
    }
  }
}

// ---- split-K reduce + activation epilogues (vectorized x4) ----
__global__ void red_sig(const float* __restrict__ P, int M,
                        unsigned short* __restrict__ out1) {
  int idx = blockIdx.x * 256 + threadIdx.x;       // float4 index
  if (idx * 4 >= M * 256) return;
  float4 a = reinterpret_cast<const float4*>(P)[idx];
  float4 b = reinterpret_cast<const float4*>(P + (size_t)M * 256)[idx];
  float v0 = 1.0f / (1.0f + __expf(-(a.x + b.x)));
  float v1 = 1.0f / (1.0f + __expf(-(a.y + b.y)));
  float v2 = 1.0f / (1.0f + __expf(-(a.z + b.z)));
  float v3 = 1.0f / (1.0f + __expf(-(a.w + b.w)));
  uint2 pk;
  pk.x = (unsigned)f2bf(v0) | ((unsigned)f2bf(v1) << 16);
  pk.y = (unsigned)f2bf(v2) | ((unsigned)f2bf(v3) << 16);
  reinterpret_cast<uint2*>(out1)[idx] = pk;
}
__global__ void red_em(const float* __restrict__ P, int M,
                       float* __restrict__ em,             // stride 512, pre-offset to col 256
                       unsigned short* __restrict__ em16)  // stride 512, pre-offset to col 256
{
  int idx = blockIdx.x * 256 + threadIdx.x;       // float4 index
  if (idx * 4 >= M * 256) return;
  float4 a = reinterpret_cast<const float4*>(P)[idx];
  float4 b = reinterpret_cast<const float4*>(P + (size_t)M * 256)[idx];
  float4 v = make_float4(a.x + b.x, a.y + b.y, a.z + b.z, a.w + b.w);
  int row = idx >> 6;            // 64 float4 per 256-col row
  int c4 = idx & 63;
  *reinterpret_cast<float4*>(em + (size_t)row * 512 + c4 * 4) = v;
  uint2 pk;
  pk.x = (unsigned)f2bf(v.x) | ((unsigned)f2bf(v.y) << 16);
  pk.y = (unsigned)f2bf(v.z) | ((unsigned)f2bf(v.w) << 16);
  *reinterpret_cast<uint2*>(em16 + (size_t)row * 512 + c4 * 4) = pk;
}

// ---- lin layer GEMM (K=512, unsplit): hidden = relu(em16 @ LWt^T + b) ----
__global__ __launch_bounds__(256) void gemm_lin(
    const unsigned short* __restrict__ A,
    const unsigned short* __restrict__ Bt,
    int M, int K,
    float* __restrict__ fout,
    const float* __restrict__ bias)
{
  __shared__ unsigned short At[64 * LDSS];
  __shared__ unsigned short Bs[128 * LDSS];
  const int tid = threadIdx.x;
  const int tileM = blockIdx.x * 64;
  const int tileN = blockIdx.y * 128;
  const int lane = tid & 63;
  const int wid = tid >> 6;
  const int wr = wid >> 1, wc = wid & 1;
  const int l15 = lane & 15, lq = lane >> 4;
  f32x4 acc[2][4] = {};
  const int nk = K >> 5;
  for (int kt = 0; kt < nk; ++kt) {
    __syncthreads();
    {
      int row = tid >> 2;
      int ko = (tid & 3) * 8;
      int gr = tileM + row;
      uint4 va = make_uint4(0u, 0u, 0u, 0u);
      if (gr < M) va = *reinterpret_cast<const uint4*>(A + (size_t)gr * K + kt * 32 + ko);
      *reinterpret_cast<uint4*>(&At[row * LDSS + ko]) = va;
#pragma unroll
      for (int p = 0; p < 2; ++p) {
        int c = tid + p * 256;
        int brow = c >> 2;
        int bko = (c & 3) * 8;
        uint4 vb = *reinterpret_cast<const uint4*>(Bt + (size_t)(tileN + brow) * K + kt * 32 + bko);
        *reinterpret_cast<uint4*>(&Bs[brow * LDSS + bko]) = vb;
      }
    }
    __syncthreads();
    bf16x8 af[2], bfr[4];
#pragma unroll
    for (int m = 0; m < 2; ++m)
      af[m] = *reinterpret_cast<const bf16x8*>(&At[(wr * 32 + m * 16 + l15) * LDSS + lq * 8]);
#pragma unroll
    for (int n = 0; n < 4; ++n)
      bfr[n] = *reinterpret_cast<const bf16x8*>(&Bs[(wc * 64 + n * 16 + l15) * LDSS + lq * 8]);
#pragma unroll
    for (int m = 0; m < 2; ++m)
#pragma unroll
      for (int n = 0; n < 4; ++n)
        acc[m][n] = __builtin_amdgcn_mfma_f32_16x16x32_bf16(af[m], bfr[n], acc[m][n], 0, 0, 0);
  }
  const int r0 = tileM + wr * 32;
  const int c0 = tileN + wc * 64;
#pragma unroll
  for (int m = 0; m < 2; ++m) {
#pragma unroll
    for (int n = 0; n < 4; ++n) {
      int col = c0 + n * 16 + l15;
      int rowb = r0 + m * 16 + lq * 4;
#pragma unroll
      for (int q = 0; q < 4; ++q) {
        int row = rowb + q;
        if (row < M) {
          float s = acc[m][n][q] + bias[col];
          fout[(size_t)row * 256 + col] = s > 0.0f ? s : 0.0f;
        }
      }
    }
  }
}

// ---------------- fc + log_softmax ----------------
__global__ __launch_bounds__(256) void fc_lsm(const float* __restrict__ hidden,
                                              const float* __restrict__ fcW,
                                              const float* __restrict__ fcb,
                                              float* __restrict__ outlp, int N) {
  __shared__ float hs[32 * 256];
  __shared__ float fw[256 * 7];
  __shared__ float lg[32][8];
  const int t = threadIdx.x;
  const int nb = blockIdx.x * 32;
  for (int c = t; c < 256 * 7; c += 256) fw[c] = fcW[c];
  for (int c = t; c < 32 * 256; c += 256) {
    int node = nb + (c >> 8);
    hs[c] = (node < N) ? hidden[(size_t)node * 256 + (c & 255)] : 0.0f;
  }
  __syncthreads();
  if (t < 224) {
    int ln = t / 7, c = t - ln * 7;
    float s = fcb[c];
    for (int h = 0; h < 256; ++h) s += hs[ln * 256 + h] * fw[h * 7 + c];
    lg[ln][c] = s;
  }
  __syncthreads();
  if (t < 32 && nb + t < N) {
    float m = lg[t][0];
    for (int c = 1; c < 7; ++c) m = fmaxf(m, lg[t][c]);
    float sum = 0.0f;
    for (int c = 0; c < 7; ++c) sum += __expf(lg[t][c] - m);
    float ls = __logf(sum);
    for (int c = 0; c < 7; ++c) outlp[(size_t)(nb + t) * 7 + c] = lg[t][c] - m - ls;
  }
}

extern "C" void kernel_launch(void* const* d_in, const int* in_sizes, int n_in,
                              void* d_out, int out_size, void* d_ws, size_t ws_size,
                              hipStream_t stream) {
  const float* x     = (const float*)d_in[1];
  const int*   ei    = (const int*)d_in[2];     // [2][E]: row0 = dst i, row1 = src j
  const float* enorm = (const float*)d_in[3];
  const int*   etype = (const int*)d_in[4];
  const float* w1    = (const float*)d_in[7];
  const float* w2    = (const float*)d_in[8];
  const float* linW  = (const float*)d_in[9];
  const float* linb  = (const float*)d_in[10];
  const float* fcW   = (const float*)d_in[11];
  const float* fcb   = (const float*)d_in[12];
  float* out = (float*)d_out;

  const int N = in_sizes[0];        // 20000
  const int E = in_sizes[3];        // 640000
  const int NB = N * 10;            // (dst,type) buckets
  const int NSCAN = (NB + 4095) / 4096;

  char* ws = (char*)d_ws;
  size_t off = 0;
  auto carve = [&](size_t bytes) -> void* {
    void* p = ws + off;
    off += (bytes + 255) & ~(size_t)255;
    return p;
  };
  unsigned short* S    = (unsigned short*)carve((size_t)N * RH * 2);
  unsigned short* W1t  = (unsigned short*)carve((size_t)256 * RH * 2);
  unsigned short* W2t  = (unsigned short*)carve((size_t)256 * RH * 2);
  unsigned short* LWt  = (unsigned short*)carve((size_t)256 * 512 * 2);
  unsigned short* out1 = (unsigned short*)carve((size_t)N * 256 * 2);
  unsigned short* em16 = (unsigned short*)carve((size_t)N * 512 * 2);
  unsigned short* x16  = (unsigned short*)carve((size_t)N * 256 * 2);
  int* cnt2            = (int*)carve((size_t)NB * 4);
  int* offs2           = (int*)carve((size_t)(NB + 1) * 4);
  int* cursor          = (int*)carve((size_t)NB * 4);
  int* bsum            = (int*)carve((size_t)1024 * 4);
  int2* jnpk           = (int2*)carve((size_t)E * 8);
  float* P             = (float*)carve((size_t)2 * N * 256 * 4);  // split-K partials
  float* hidden        = (float*)S;   // alias: S dead after gemm_sk(2), hidden born at gemm_lin

  const int* e_i = ei;       // destination (aggregate here)
  const int* e_j = ei + E;   // source (gather x here)

  // (dst,type) CSR + payload sort
  zero_int<<<(NB + 255) / 256, 256, 0, stream>>>(cnt2, NB);
  hist_kernel<<<(E + 255) / 256, 256, 0, stream>>>(e_i, etype, E, cnt2);
  scan_local<<<NSCAN, 1024, 0, stream>>>(cnt2, offs2, bsum, NB);
  scan_bsum<<<1, 1024, 0, stream>>>(bsum, offs2, NSCAN, NB);
  scan_add<<<NSCAN, 1024, 0, stream>>>(offs2, cursor, bsum, NB);
  scatter_kernel<<<(E + 255) / 256, 256, 0, stream>>>(e_i, e_j, etype, enorm, E,
                                                      cursor, jnpk);

  // weight packing + x copies
  const int PACKTOT = 2 * 256 * RH + 256 * 512;
  pack_all<<<(PACKTOT + 255) / 256, 256, 0, stream>>>(w1, w2, linW, W1t, W2t, LWt);
  copyX<<<((N * 256) + 255) / 256, 256, 0, stream>>>(
      x, out + (size_t)N * 7, out + (size_t)N * 263, em16, x16, N * 256);

  dim3 sk_grid((N + 63) / 64, 2, 2);
  const int RED_BLK = ((N * 256 / 4) + 255) / 256;

  // layer 1
  agg_bucket<<<(NB + 3) / 4, 256, 0, stream>>>(x16, offs2, jnpk, S, NB);
  gemm_sk<<<sk_grid, 256, 0, stream>>>(S, W1t, N, RH, P);
  red_sig<<<RED_BLK, 256, 0, stream>>>(P, N, out1);

  // layer 2 -> emotions[:, 256:512] (f32 into d_out) + bf16 copy into em16
  agg_bucket<<<(NB + 3) / 4, 256, 0, stream>>>(out1, offs2, jnpk, S, NB);
  gemm_sk<<<sk_grid, 256, 0, stream>>>(S, W2t, N, RH, P);
  red_em<<<RED_BLK, 256, 0, stream>>>(P, N, out + (size_t)N * 263 + 256, em16 + 256);

  // hidden = relu(emotions @ lin_W + lin_b)
  dim3 lin_grid((N + 63) / 64, 2);
  gemm_lin<<<lin_grid, 256, 0, stream>>>(em16, LWt, N, 512, hidden, linb);

  // logits + log_softmax
  fc_lsm<<<(N + 31) / 32, 256, 0, stream>>>(hidden, fcW, fcb, out, N);
}